// Round 6
// baseline (225.698 us; speedup 1.0000x reference)
//
#include <hip/hip_runtime.h>
#include <hip/hip_bf16.h>

// ModularPathwayConv round 6:
//  R5 post-mortem: precompute_ab 51us is LDS-ISSUE-bound (512 ds_read_b128/wave,
//  only 8 FMA per LDS inst; ~6250 waves x 6144 LDS-cyc / 256 CU = measured 51us).
//  Fix: 8 nodes/thread, A|Bp halves split across lanes -> 32 FMA per LDS inst,
//  FMA-bound at the ~10us fp32 floor. +4-float LDS pad between W1 halves so the
//  (q,half) wave-uniform addresses alias only 2-way (free, m136).

constexpr int TPB = 256;
constexpr int SCAN_B = 1024;

// ---------------- CSR build ----------------

__global__ void hist_rank(const int* __restrict__ ei, int* __restrict__ cnt,
                          int* __restrict__ rank, int E) {
  int e = blockIdx.x * blockDim.x + threadIdx.x;
  if (e < E) rank[e] = atomicAdd(&cnt[ei[E + e]], 1);
}

__global__ __launch_bounds__(SCAN_B) void scan_local(const int* __restrict__ cnt,
                                                     int* __restrict__ off,
                                                     int* __restrict__ bsum, int N) {
  __shared__ int s[SCAN_B];
  int i = blockIdx.x * SCAN_B + (int)threadIdx.x;
  int v = (i < N) ? cnt[i] : 0;
  s[threadIdx.x] = v;
  __syncthreads();
  for (int d = 1; d < SCAN_B; d <<= 1) {
    int t = (threadIdx.x >= d) ? s[threadIdx.x - d] : 0;
    __syncthreads();
    s[threadIdx.x] += t;
    __syncthreads();
  }
  if (i < N) off[i] = s[threadIdx.x] - v;
  if (threadIdx.x == SCAN_B - 1) bsum[blockIdx.x] = s[threadIdx.x];
}

__global__ __launch_bounds__(SCAN_B) void scan_bsum(int* __restrict__ bsum, int nb) {
  __shared__ int s[SCAN_B];
  int v = ((int)threadIdx.x < nb) ? bsum[threadIdx.x] : 0;
  s[threadIdx.x] = v;
  __syncthreads();
  for (int d = 1; d < SCAN_B; d <<= 1) {
    int t = (threadIdx.x >= d) ? s[threadIdx.x - d] : 0;
    __syncthreads();
    s[threadIdx.x] += t;
    __syncthreads();
  }
  if ((int)threadIdx.x < nb) bsum[threadIdx.x] = s[threadIdx.x] - v;
}

__global__ void scatter_edges(const int* __restrict__ ei, const float* __restrict__ ea,
                              const int* __restrict__ off, const int* __restrict__ bsum,
                              const int* __restrict__ rank, int2* __restrict__ sre, int E) {
  int e = blockIdx.x * blockDim.x + threadIdx.x;
  if (e >= E) return;
  int col = ei[E + e];
  int pos = off[col] + bsum[col >> 10] + rank[e];
  sre[pos] = make_int2(ei[e], __float_as_int(ea[e]));
}

// ---------------- bf16 pack helper ----------------

__device__ inline unsigned int pack_bf16(float lo, float hi) {
  __hip_bfloat16 l = __float2bfloat16(lo);
  __hip_bfloat16 h = __float2bfloat16(hi);
  unsigned short lu = *reinterpret_cast<unsigned short*>(&l);
  unsigned short hu = *reinterpret_cast<unsigned short*>(&h);
  return (unsigned int)lu | ((unsigned int)hu << 16);
}

// ---------------- per-node precompute: A = x@W1_top, Bp = x@W1_bot + b1 (bf16 out) ---
// Lane layout: lane = nodeblock8*8 + half*4 + q. Thread computes 16 channels
// (chunk q) of either A (half=0) or Bp (half=1) for 8 consecutive nodes.
// W1 halves padded apart by 4 floats in LDS -> 2-way bank aliasing only.

constexpr int W1_HALF = 64 * 64;      // floats per half
constexpr int W1_PAD  = 4;            // bank shift between halves

__global__ __launch_bounds__(TPB) void precompute_ab(
    const float* __restrict__ x, const float* __restrict__ W1,
    const float* __restrict__ b1, unsigned int* __restrict__ Abf,
    unsigned int* __restrict__ Bpbf, int N)
{
  __shared__ float sW1[2 * W1_HALF + W1_PAD];
  __shared__ float sB1[64];
  // stage: float4 i<1024 -> slot i (top half); i>=1024 -> slot i+1 (bottom, +4 floats)
  for (int i = threadIdx.x; i < 2048; i += TPB) {
    float4 v = reinterpret_cast<const float4*>(W1)[i];
    reinterpret_cast<float4*>(sW1)[i < 1024 ? i : i + 1] = v;
  }
  if (threadIdx.x < 64) sB1[threadIdx.x] = b1[threadIdx.x];
  __syncthreads();

  const int g = blockIdx.x * TPB + (int)threadIdx.x;
  const int nb8 = g >> 3;
  const int half = (g >> 2) & 1;      // 0 = A, 1 = Bp (+b1)
  const int q = g & 3;                // 16-channel chunk
  const int n0 = nb8 * 8;
  if (n0 >= N) return;
  const int nmax = (N - n0 < 8) ? (N - n0) : 8;

  float acc[8][16];
#pragma unroll
  for (int n = 0; n < 8; ++n) {
#pragma unroll
    for (int j = 0; j < 16; ++j)
      acc[n][j] = half ? sB1[q * 16 + j] : 0.0f;
  }

  const float* wbase = sW1 + half * (W1_HALF + W1_PAD) + q * 16;
  const float* xbase = x + (size_t)n0 * 64;

  for (int kc = 0; kc < 16; ++kc) {
    float4 xv[8];
#pragma unroll
    for (int n = 0; n < 8; ++n)
      xv[n] = (n < nmax)
                  ? *reinterpret_cast<const float4*>(xbase + n * 64 + kc * 4)
                  : make_float4(0.f, 0.f, 0.f, 0.f);
#pragma unroll
    for (int kk = 0; kk < 4; ++kk) {
      const int k = kc * 4 + kk;
      const float* wr = wbase + k * 64;
      float4 w0 = *reinterpret_cast<const float4*>(wr);
      float4 w1 = *reinterpret_cast<const float4*>(wr + 4);
      float4 w2 = *reinterpret_cast<const float4*>(wr + 8);
      float4 w3 = *reinterpret_cast<const float4*>(wr + 12);
      const float w[16] = {w0.x, w0.y, w0.z, w0.w, w1.x, w1.y, w1.z, w1.w,
                           w2.x, w2.y, w2.z, w2.w, w3.x, w3.y, w3.z, w3.w};
#pragma unroll
      for (int n = 0; n < 8; ++n) {
        const float c0 = (&xv[n].x)[kk];
#pragma unroll
        for (int j = 0; j < 16; ++j)
          acc[n][j] = fmaf(c0, w[j], acc[n][j]);
      }
    }
  }

  unsigned int* dst = half ? Bpbf : Abf;
#pragma unroll
  for (int n = 0; n < 8; ++n) {
    if (n >= nmax) break;
    uint4 p0, p1;
    unsigned int* p0w = &p0.x;
    unsigned int* p1w = &p1.x;
#pragma unroll
    for (int j = 0; j < 4; ++j) {
      p0w[j] = pack_bf16(acc[n][2 * j], acc[n][2 * j + 1]);
      p1w[j] = pack_bf16(acc[n][8 + 2 * j], acc[n][8 + 2 * j + 1]);
    }
    uint4* drow = reinterpret_cast<uint4*>(dst) + (size_t)(n0 + n) * 8 + q * 2;
    drow[0] = p0;
    drow[1] = p1;
  }
}

// ---------------- fused: H[n]=sum relu(ea*A[row]+Bp[n]); out[n]=H@W2+deg*b2 ----------------

__global__ __launch_bounds__(TPB) void node_accum_gemm(
    const unsigned int* __restrict__ Abf, const unsigned int* __restrict__ Bpbf,
    const int2* __restrict__ sre, const int* __restrict__ off,
    const int* __restrict__ bsum, const int* __restrict__ cnt,
    const float* __restrict__ W2, const float* __restrict__ b2,
    float* __restrict__ out, int N)
{
  __shared__ float sW2[64 * 64];    // 16 KB
  __shared__ float sB2[64];
  for (int i = threadIdx.x; i < 64 * 64 / 4; i += TPB)
    reinterpret_cast<float4*>(sW2)[i] = reinterpret_cast<const float4*>(W2)[i];
  if (threadIdx.x < 64) sB2[threadIdx.x] = b2[threadIdx.x];
  __syncthreads();

  const int g = blockIdx.x * TPB + (int)threadIdx.x;
  const int n = g >> 2;
  const int q = g & 3;
  if (n >= N) return;

  const int start = off[n] + bsum[n >> 10];
  const int deg = cnt[n];

  float bpf[16];
  {
    const uint4* brow = reinterpret_cast<const uint4*>(Bpbf) + (size_t)n * 8 + q * 2;
    uint4 b0 = brow[0], b1v = brow[1];
    const unsigned int bu[8] = {b0.x, b0.y, b0.z, b0.w, b1v.x, b1v.y, b1v.z, b1v.w};
#pragma unroll
    for (int j = 0; j < 8; ++j) {
      bpf[2 * j]     = __uint_as_float(bu[j] << 16);
      bpf[2 * j + 1] = __uint_as_float(bu[j] & 0xffff0000u);
    }
  }

  float acc[16];
#pragma unroll
  for (int j = 0; j < 16; ++j) acc[j] = 0.f;

  int2 e0 = (deg > 0) ? sre[start] : make_int2(0, 0);
  const uint4* ar0 = reinterpret_cast<const uint4*>(Abf) + (size_t)e0.x * 8 + q * 2;
  uint4 A0 = ar0[0], A1 = ar0[1];

  for (int t = 0; t < deg; ++t) {
    const float eav = __int_as_float(e0.y);
    uint4 C0 = A0, C1 = A1;
    if (t + 1 < deg) {
      int2 e1 = sre[start + t + 1];
      const uint4* ar1 =
          reinterpret_cast<const uint4*>(Abf) + (size_t)e1.x * 8 + q * 2;
      A0 = ar1[0]; A1 = ar1[1];
      e0 = e1;
    }
    const unsigned int au[8] = {C0.x, C0.y, C0.z, C0.w, C1.x, C1.y, C1.z, C1.w};
#pragma unroll
    for (int j = 0; j < 8; ++j) {
      float lo = __uint_as_float(au[j] << 16);
      float hi = __uint_as_float(au[j] & 0xffff0000u);
      acc[2 * j]     += fmaxf(fmaf(eav, lo, bpf[2 * j]), 0.f);
      acc[2 * j + 1] += fmaxf(fmaf(eav, hi, bpf[2 * j + 1]), 0.f);
    }
  }

  // fused second GEMM: lane q owns H chunk q, produces out ch [16q,16q+16)
  float m[16];
  {
    const float degf = (float)deg;
#pragma unroll
    for (int j = 0; j < 16; j += 4) {
      float4 b = *reinterpret_cast<const float4*>(sB2 + q * 16 + j);
      m[j] = degf * b.x; m[j + 1] = degf * b.y;
      m[j + 2] = degf * b.z; m[j + 3] = degf * b.w;
    }
  }
#pragma unroll
  for (int s = 0; s < 4; ++s) {
    const int r = q ^ s;
    float hc[16];
#pragma unroll
    for (int j = 0; j < 16; ++j)
      hc[j] = (s == 0) ? acc[j] : __shfl_xor(acc[j], s);
#pragma unroll
    for (int kk = 0; kk < 16; ++kk) {
      const float hk = hc[kk];
      const float* wr = sW2 + (16 * r + kk) * 64 + q * 16;
#pragma unroll
      for (int j = 0; j < 16; j += 4) {
        float4 w = *reinterpret_cast<const float4*>(wr + j);
        m[j]     = fmaf(hk, w.x, m[j]);
        m[j + 1] = fmaf(hk, w.y, m[j + 1]);
        m[j + 2] = fmaf(hk, w.z, m[j + 2]);
        m[j + 3] = fmaf(hk, w.w, m[j + 3]);
      }
    }
  }

  float4* orow = reinterpret_cast<float4*>(out + (size_t)n * 64) + q * 4;
#pragma unroll
  for (int j = 0; j < 16; j += 4)
    orow[j / 4] = make_float4(m[j], m[j + 1], m[j + 2], m[j + 3]);
}

// ---------------- fallback (round-1 path, if ws too small) ----------------

__global__ __launch_bounds__(TPB) void edge_mlp_atomic(
    const float* __restrict__ x, const int* __restrict__ ei,
    const float* __restrict__ eattr, const float* __restrict__ W1,
    const float* __restrict__ b1, const float* __restrict__ W2,
    const float* __restrict__ b2, float* __restrict__ out, int E)
{
  __shared__ float sW1[128 * 64];
  __shared__ float sW2[64 * 64];
  __shared__ float sB1[64];
  __shared__ float sB2[64];
  for (int i = threadIdx.x; i < 128 * 64 / 4; i += TPB)
    reinterpret_cast<float4*>(sW1)[i] = reinterpret_cast<const float4*>(W1)[i];
  for (int i = threadIdx.x; i < 64 * 64 / 4; i += TPB)
    reinterpret_cast<float4*>(sW2)[i] = reinterpret_cast<const float4*>(W2)[i];
  if (threadIdx.x < 64) { sB1[threadIdx.x] = b1[threadIdx.x]; sB2[threadIdx.x] = b2[threadIdx.x]; }
  __syncthreads();
  const int e = blockIdx.x * TPB + (int)threadIdx.x;
  if (e >= E) return;
  const int row = ei[e];
  const int col = ei[E + e];
  const float scale = eattr[e];
  float h[64];
#pragma unroll
  for (int o = 0; o < 64; ++o) h[o] = sB1[o];
#pragma unroll
  for (int half = 0; half < 2; ++half) {
    const float4* src = reinterpret_cast<const float4*>(x + (size_t)(half ? col : row) * 64);
    const float sc = half ? 1.0f : scale;
    const float* wb = sW1 + half * 64 * 64;
    for (int kc = 0; kc < 16; ++kc) {
      float4 cv = src[kc];
      cv.x *= sc; cv.y *= sc; cv.z *= sc; cv.w *= sc;
      const float* wr = wb + kc * 4 * 64;
#pragma unroll
      for (int kk = 0; kk < 4; ++kk) {
        const float c = (&cv.x)[kk];
#pragma unroll
        for (int o = 0; o < 64; ++o) h[o] = fmaf(c, wr[kk * 64 + o], h[o]);
      }
    }
  }
#pragma unroll
  for (int o = 0; o < 64; ++o) h[o] = fmaxf(h[o], 0.0f);
  float* outrow = out + (size_t)col * 64;
#pragma unroll
  for (int oc = 0; oc < 4; ++oc) {
    float m[16];
#pragma unroll
    for (int j = 0; j < 16; ++j) m[j] = sB2[oc * 16 + j];
#pragma unroll
    for (int k = 0; k < 64; ++k) {
      const float hk = h[k];
      const float* wr = sW2 + k * 64 + oc * 16;
#pragma unroll
      for (int j = 0; j < 16; ++j) m[j] = fmaf(hk, wr[j], m[j]);
    }
#pragma unroll
    for (int j = 0; j < 16; ++j) atomicAdd(outrow + oc * 16 + j, m[j]);
  }
}

// ---------------- launch ----------------

extern "C" void kernel_launch(void* const* d_in, const int* in_sizes, int n_in,
                              void* d_out, int out_size, void* d_ws, size_t ws_size,
                              hipStream_t stream) {
  const float* x  = (const float*)d_in[0];
  const int*   ei = (const int*)d_in[1];   // [2,E] int32
  const float* ea = (const float*)d_in[2];
  const float* W1 = (const float*)d_in[3];
  const float* b1 = (const float*)d_in[4];
  const float* W2 = (const float*)d_in[5];
  const float* b2 = (const float*)d_in[6];
  float* out = (float*)d_out;
  const int E = in_sizes[2];
  const int N = in_sizes[0] / 64;
  const int nb = (N + SCAN_B - 1) / SCAN_B;

  // ws layout: sre[E] int2 | rank[E] | cnt[N] | off[N] | bsum[SCAN_B]
  //            | Abf[N*32 u32] | Bpbf[N*32 u32]
  auto align16 = [](size_t v) { return (v + 15) & ~(size_t)15; };
  size_t o_sre  = 0;
  size_t o_rank = align16(o_sre + (size_t)E * 8);
  size_t o_cnt  = align16(o_rank + (size_t)E * 4);
  size_t o_off  = align16(o_cnt + (size_t)N * 4);
  size_t o_bsum = align16(o_off + (size_t)N * 4);
  size_t o_A    = align16(o_bsum + (size_t)SCAN_B * 4);
  size_t o_Bp   = align16(o_A + (size_t)N * 128);
  size_t need   = o_Bp + (size_t)N * 128;

  if (ws_size < need || nb > SCAN_B) {
    hipMemsetAsync(d_out, 0, (size_t)out_size * sizeof(float), stream);
    const int blocks = (E + TPB - 1) / TPB;
    edge_mlp_atomic<<<blocks, TPB, 0, stream>>>(x, ei, ea, W1, b1, W2, b2, out, E);
    return;
  }

  char* ws = (char*)d_ws;
  int2* sre  = (int2*)(ws + o_sre);
  int*  rank = (int*)(ws + o_rank);
  int*  cnt  = (int*)(ws + o_cnt);
  int*  off  = (int*)(ws + o_off);
  int*  bsum = (int*)(ws + o_bsum);
  unsigned int* Abf  = (unsigned int*)(ws + o_A);
  unsigned int* Bpbf = (unsigned int*)(ws + o_Bp);

  hipMemsetAsync(cnt, 0, (size_t)N * sizeof(int), stream);

  const int eblocks = (E + TPB - 1) / TPB;
  const int nblocks4 = (4 * N + TPB - 1) / TPB;
  const int nblocks8 = ((N + 7) / 8 * 8 + TPB - 1) / TPB;   // 8 lanes per 8-node block

  hist_rank<<<eblocks, TPB, 0, stream>>>(ei, cnt, rank, E);
  scan_local<<<nb, SCAN_B, 0, stream>>>(cnt, off, bsum, N);
  scan_bsum<<<1, SCAN_B, 0, stream>>>(bsum, nb);
  scatter_edges<<<eblocks, TPB, 0, stream>>>(ei, ea, off, bsum, rank, sre, E);
  precompute_ab<<<nblocks8, TPB, 0, stream>>>(x, W1, b1, Abf, Bpbf, N);
  node_accum_gemm<<<nblocks4, TPB, 0, stream>>>(Abf, Bpbf, sre, off, bsum, cnt,
                                                W2, b2, out, N);
}

// Round 7
// 204.932 us; speedup vs baseline: 1.1013x; 1.1013x over previous
//
#include <hip/hip_runtime.h>

// ModularPathwayConv round 7:
//  R6 post-mortem: 8-node VALU precompute REGRESSED (bank conflicts 400K,
//  VGPR 124 -> occupancy 12%, FETCH 2.3x). Step back: precompute is a dense
//  [N,64]@[64,128] GEMM -> use MFMA (guideline 10). bf16 16x16x32, W1 frags
//  pre-swizzled in LDS (read once into regs), x converted to bf16 inline.
//  Memory-bound floor ~51MB / 6.3TB/s ~ 8us (vs 51-64us VALU versions).

constexpr int TPB = 256;
constexpr int SCAN_B = 1024;

typedef __attribute__((ext_vector_type(8))) short short8;
typedef __attribute__((ext_vector_type(4))) float f32x4;

// fp32 -> bf16 round-to-nearest-even (manual, avoids API differences)
__device__ inline unsigned short f2bf(float f) {
  unsigned u = __float_as_uint(f);
  unsigned r = u + 0x7fffu + ((u >> 16) & 1u);
  return (unsigned short)(r >> 16);
}

// ---------------- CSR build ----------------

__global__ void hist_rank(const int* __restrict__ ei, int* __restrict__ cnt,
                          int* __restrict__ rank, int E) {
  int e = blockIdx.x * blockDim.x + threadIdx.x;
  if (e < E) rank[e] = atomicAdd(&cnt[ei[E + e]], 1);
}

__global__ __launch_bounds__(SCAN_B) void scan_local(const int* __restrict__ cnt,
                                                     int* __restrict__ off,
                                                     int* __restrict__ bsum, int N) {
  __shared__ int s[SCAN_B];
  int i = blockIdx.x * SCAN_B + (int)threadIdx.x;
  int v = (i < N) ? cnt[i] : 0;
  s[threadIdx.x] = v;
  __syncthreads();
  for (int d = 1; d < SCAN_B; d <<= 1) {
    int t = (threadIdx.x >= d) ? s[threadIdx.x - d] : 0;
    __syncthreads();
    s[threadIdx.x] += t;
    __syncthreads();
  }
  if (i < N) off[i] = s[threadIdx.x] - v;
  if (threadIdx.x == SCAN_B - 1) bsum[blockIdx.x] = s[threadIdx.x];
}

__global__ __launch_bounds__(SCAN_B) void scan_bsum(int* __restrict__ bsum, int nb) {
  __shared__ int s[SCAN_B];
  int v = ((int)threadIdx.x < nb) ? bsum[threadIdx.x] : 0;
  s[threadIdx.x] = v;
  __syncthreads();
  for (int d = 1; d < SCAN_B; d <<= 1) {
    int t = (threadIdx.x >= d) ? s[threadIdx.x - d] : 0;
    __syncthreads();
    s[threadIdx.x] += t;
    __syncthreads();
  }
  if ((int)threadIdx.x < nb) bsum[threadIdx.x] = s[threadIdx.x] - v;
}

__global__ void scatter_edges(const int* __restrict__ ei, const float* __restrict__ ea,
                              const int* __restrict__ off, const int* __restrict__ bsum,
                              const int* __restrict__ rank, int2* __restrict__ sre, int E) {
  int e = blockIdx.x * blockDim.x + threadIdx.x;
  if (e >= E) return;
  int col = ei[E + e];
  int pos = off[col] + bsum[col >> 10] + rank[e];
  sre[pos] = make_int2(ei[e], __float_as_int(ea[e]));
}

// ---------------- precompute via MFMA: A = x@W1_top, Bp = x@W1_bot + b1 ----
// One wave per 16-node tile, all 128 output channels (8 col-tiles x K=64).
// bfrag layouts per docs: A[m=lane&15][k=quad*8+j]; B[k=quad*8+j][n=lane&15];
// C/D col=lane&15, row=quad*4+reg (m89/m91/m120 verified mappings).

__global__ __launch_bounds__(TPB) void precompute_mfma(
    const float* __restrict__ x, const float* __restrict__ W1,
    const float* __restrict__ b1,
    unsigned short* __restrict__ Abf, unsigned short* __restrict__ Bpbf, int N)
{
  // pre-swizzled B fragments: [ct][ks][lane][j] bf16, per-lane contiguous 16B
  __shared__ unsigned short sFrag[8 * 2 * 64 * 8];   // 16 KB

  for (int idx = threadIdx.x; idx < 8192; idx += TPB) {
    const int j  = idx & 7;
    const int l  = (idx >> 3) & 63;
    const int ks = (idx >> 9) & 1;
    const int ct = idx >> 10;
    const int k  = ks * 32 + ((l >> 4) << 3) + j;     // K index within 64
    const int r  = k + 64 * (ct >> 2);                // W1 row (half select)
    const int c  = (ct & 3) * 16 + (l & 15);          // W1 col
    sFrag[idx] = f2bf(W1[r * 64 + c]);
  }
  __syncthreads();

  const int w = threadIdx.x >> 6;
  const int l = threadIdx.x & 63;
  const int q = l >> 4;
  const int m = l & 15;
  const int n0 = (blockIdx.x * 4 + w) * 16;
  if (n0 >= N) return;

  short8 bfrag[8][2];
#pragma unroll
  for (int ct = 0; ct < 8; ++ct)
#pragma unroll
    for (int ks = 0; ks < 2; ++ks)
      bfrag[ct][ks] =
          *reinterpret_cast<const short8*>(&sFrag[(ct * 2 + ks) * 512 + l * 8]);

  // A fragments: row n0+m of x, k = ks*32 + q*8 + j (bf16-rounded)
  const int nA = (n0 + m < N) ? (n0 + m) : (N - 1);   // clamped rows never stored
  const float* xr = x + (size_t)nA * 64 + q * 8;
  short8 afrag[2];
#pragma unroll
  for (int ks = 0; ks < 2; ++ks) {
    float4 v0 = *reinterpret_cast<const float4*>(xr + ks * 32);
    float4 v1 = *reinterpret_cast<const float4*>(xr + ks * 32 + 4);
    short8 a;
    a[0] = (short)f2bf(v0.x); a[1] = (short)f2bf(v0.y);
    a[2] = (short)f2bf(v0.z); a[3] = (short)f2bf(v0.w);
    a[4] = (short)f2bf(v1.x); a[5] = (short)f2bf(v1.y);
    a[6] = (short)f2bf(v1.z); a[7] = (short)f2bf(v1.w);
    afrag[ks] = a;
  }

  f32x4 acc[8];
#pragma unroll
  for (int ct = 0; ct < 8; ++ct) {
    const float bv = (ct >= 4) ? b1[(ct - 4) * 16 + m] : 0.0f;
    acc[ct] = (f32x4){bv, bv, bv, bv};
  }

#pragma unroll
  for (int ct = 0; ct < 8; ++ct)
#pragma unroll
    for (int ks = 0; ks < 2; ++ks)
      acc[ct] = __builtin_amdgcn_mfma_f32_16x16x32_bf16(
          afrag[ks], bfrag[ct][ks], acc[ct], 0, 0, 0);

  // store: D row = node-local q*4+r, col = ch-local m
#pragma unroll
  for (int ct = 0; ct < 8; ++ct) {
    unsigned short* dst = (ct < 4) ? Abf : Bpbf;
    const int ch = (ct & 3) * 16 + m;
#pragma unroll
    for (int r = 0; r < 4; ++r) {
      const int node = n0 + q * 4 + r;
      if (node < N) dst[(size_t)node * 64 + ch] = f2bf(acc[ct][r]);
    }
  }
}

// ---------------- fused: H[n]=sum relu(ea*A[row]+Bp[n]); out[n]=H@W2+deg*b2 ----------------

__global__ __launch_bounds__(TPB) void node_accum_gemm(
    const unsigned int* __restrict__ Abf, const unsigned int* __restrict__ Bpbf,
    const int2* __restrict__ sre, const int* __restrict__ off,
    const int* __restrict__ bsum, const int* __restrict__ cnt,
    const float* __restrict__ W2, const float* __restrict__ b2,
    float* __restrict__ out, int N)
{
  __shared__ float sW2[64 * 64];    // 16 KB
  __shared__ float sB2[64];
  for (int i = threadIdx.x; i < 64 * 64 / 4; i += TPB)
    reinterpret_cast<float4*>(sW2)[i] = reinterpret_cast<const float4*>(W2)[i];
  if (threadIdx.x < 64) sB2[threadIdx.x] = b2[threadIdx.x];
  __syncthreads();

  const int g = blockIdx.x * TPB + (int)threadIdx.x;
  const int n = g >> 2;
  const int q = g & 3;
  if (n >= N) return;

  const int start = off[n] + bsum[n >> 10];
  const int deg = cnt[n];

  float bpf[16];
  {
    const uint4* brow = reinterpret_cast<const uint4*>(Bpbf) + (size_t)n * 8 + q * 2;
    uint4 b0 = brow[0], b1v = brow[1];
    const unsigned int bu[8] = {b0.x, b0.y, b0.z, b0.w, b1v.x, b1v.y, b1v.z, b1v.w};
#pragma unroll
    for (int j = 0; j < 8; ++j) {
      bpf[2 * j]     = __uint_as_float(bu[j] << 16);
      bpf[2 * j + 1] = __uint_as_float(bu[j] & 0xffff0000u);
    }
  }

  float acc[16];
#pragma unroll
  for (int j = 0; j < 16; ++j) acc[j] = 0.f;

  int2 e0 = (deg > 0) ? sre[start] : make_int2(0, 0);
  const uint4* ar0 = reinterpret_cast<const uint4*>(Abf) + (size_t)e0.x * 8 + q * 2;
  uint4 A0 = ar0[0], A1 = ar0[1];

  for (int t = 0; t < deg; ++t) {
    const float eav = __int_as_float(e0.y);
    uint4 C0 = A0, C1 = A1;
    if (t + 1 < deg) {
      int2 e1 = sre[start + t + 1];
      const uint4* ar1 =
          reinterpret_cast<const uint4*>(Abf) + (size_t)e1.x * 8 + q * 2;
      A0 = ar1[0]; A1 = ar1[1];
      e0 = e1;
    }
    const unsigned int au[8] = {C0.x, C0.y, C0.z, C0.w, C1.x, C1.y, C1.z, C1.w};
#pragma unroll
    for (int j = 0; j < 8; ++j) {
      float lo = __uint_as_float(au[j] << 16);
      float hi = __uint_as_float(au[j] & 0xffff0000u);
      acc[2 * j]     += fmaxf(fmaf(eav, lo, bpf[2 * j]), 0.f);
      acc[2 * j + 1] += fmaxf(fmaf(eav, hi, bpf[2 * j + 1]), 0.f);
    }
  }

  // fused second GEMM: lane q owns H chunk q, produces out ch [16q,16q+16)
  float m[16];
  {
    const float degf = (float)deg;
#pragma unroll
    for (int j = 0; j < 16; j += 4) {
      float4 b = *reinterpret_cast<const float4*>(sB2 + q * 16 + j);
      m[j] = degf * b.x; m[j + 1] = degf * b.y;
      m[j + 2] = degf * b.z; m[j + 3] = degf * b.w;
    }
  }
#pragma unroll
  for (int s = 0; s < 4; ++s) {
    const int r = q ^ s;
    float hc[16];
#pragma unroll
    for (int j = 0; j < 16; ++j)
      hc[j] = (s == 0) ? acc[j] : __shfl_xor(acc[j], s);
#pragma unroll
    for (int kk = 0; kk < 16; ++kk) {
      const float hk = hc[kk];
      const float* wr = sW2 + (16 * r + kk) * 64 + q * 16;
#pragma unroll
      for (int j = 0; j < 16; j += 4) {
        float4 w = *reinterpret_cast<const float4*>(wr + j);
        m[j]     = fmaf(hk, w.x, m[j]);
        m[j + 1] = fmaf(hk, w.y, m[j + 1]);
        m[j + 2] = fmaf(hk, w.z, m[j + 2]);
        m[j + 3] = fmaf(hk, w.w, m[j + 3]);
      }
    }
  }

  float4* orow = reinterpret_cast<float4*>(out + (size_t)n * 64) + q * 4;
#pragma unroll
  for (int j = 0; j < 16; j += 4)
    orow[j / 4] = make_float4(m[j], m[j + 1], m[j + 2], m[j + 3]);
}

// ---------------- fallback (round-1 path, if ws too small) ----------------

__global__ __launch_bounds__(TPB) void edge_mlp_atomic(
    const float* __restrict__ x, const int* __restrict__ ei,
    const float* __restrict__ eattr, const float* __restrict__ W1,
    const float* __restrict__ b1, const float* __restrict__ W2,
    const float* __restrict__ b2, float* __restrict__ out, int E)
{
  __shared__ float sW1[128 * 64];
  __shared__ float sW2[64 * 64];
  __shared__ float sB1[64];
  __shared__ float sB2[64];
  for (int i = threadIdx.x; i < 128 * 64 / 4; i += TPB)
    reinterpret_cast<float4*>(sW1)[i] = reinterpret_cast<const float4*>(W1)[i];
  for (int i = threadIdx.x; i < 64 * 64 / 4; i += TPB)
    reinterpret_cast<float4*>(sW2)[i] = reinterpret_cast<const float4*>(W2)[i];
  if (threadIdx.x < 64) { sB1[threadIdx.x] = b1[threadIdx.x]; sB2[threadIdx.x] = b2[threadIdx.x]; }
  __syncthreads();
  const int e = blockIdx.x * TPB + (int)threadIdx.x;
  if (e >= E) return;
  const int row = ei[e];
  const int col = ei[E + e];
  const float scale = eattr[e];
  float h[64];
#pragma unroll
  for (int o = 0; o < 64; ++o) h[o] = sB1[o];
#pragma unroll
  for (int half = 0; half < 2; ++half) {
    const float4* src = reinterpret_cast<const float4*>(x + (size_t)(half ? col : row) * 64);
    const float sc = half ? 1.0f : scale;
    const float* wb = sW1 + half * 64 * 64;
    for (int kc = 0; kc < 16; ++kc) {
      float4 cv = src[kc];
      cv.x *= sc; cv.y *= sc; cv.z *= sc; cv.w *= sc;
      const float* wr = wb + kc * 4 * 64;
#pragma unroll
      for (int kk = 0; kk < 4; ++kk) {
        const float c = (&cv.x)[kk];
#pragma unroll
        for (int o = 0; o < 64; ++o) h[o] = fmaf(c, wr[kk * 64 + o], h[o]);
      }
    }
  }
#pragma unroll
  for (int o = 0; o < 64; ++o) h[o] = fmaxf(h[o], 0.0f);
  float* outrow = out + (size_t)col * 64;
#pragma unroll
  for (int oc = 0; oc < 4; ++oc) {
    float m[16];
#pragma unroll
    for (int j = 0; j < 16; ++j) m[j] = sB2[oc * 16 + j];
#pragma unroll
    for (int k = 0; k < 64; ++k) {
      const float hk = h[k];
      const float* wr = sW2 + k * 64 + oc * 16;
#pragma unroll
      for (int j = 0; j < 16; ++j) m[j] = fmaf(hk, wr[j], m[j]);
    }
#pragma unroll
    for (int j = 0; j < 16; ++j) atomicAdd(outrow + oc * 16 + j, m[j]);
  }
}

// ---------------- launch ----------------

extern "C" void kernel_launch(void* const* d_in, const int* in_sizes, int n_in,
                              void* d_out, int out_size, void* d_ws, size_t ws_size,
                              hipStream_t stream) {
  const float* x  = (const float*)d_in[0];
  const int*   ei = (const int*)d_in[1];   // [2,E] int32
  const float* ea = (const float*)d_in[2];
  const float* W1 = (const float*)d_in[3];
  const float* b1 = (const float*)d_in[4];
  const float* W2 = (const float*)d_in[5];
  const float* b2 = (const float*)d_in[6];
  float* out = (float*)d_out;
  const int E = in_sizes[2];
  const int N = in_sizes[0] / 64;
  const int nb = (N + SCAN_B - 1) / SCAN_B;

  // ws layout: sre[E] int2 | rank[E] | cnt[N] | off[N] | bsum[SCAN_B]
  //            | Abf[N*64 u16] | Bpbf[N*64 u16]
  auto align16 = [](size_t v) { return (v + 15) & ~(size_t)15; };
  size_t o_sre  = 0;
  size_t o_rank = align16(o_sre + (size_t)E * 8);
  size_t o_cnt  = align16(o_rank + (size_t)E * 4);
  size_t o_off  = align16(o_cnt + (size_t)N * 4);
  size_t o_bsum = align16(o_off + (size_t)N * 4);
  size_t o_A    = align16(o_bsum + (size_t)SCAN_B * 4);
  size_t o_Bp   = align16(o_A + (size_t)N * 128);
  size_t need   = o_Bp + (size_t)N * 128;

  if (ws_size < need || nb > SCAN_B) {
    hipMemsetAsync(d_out, 0, (size_t)out_size * sizeof(float), stream);
    const int blocks = (E + TPB - 1) / TPB;
    edge_mlp_atomic<<<blocks, TPB, 0, stream>>>(x, ei, ea, W1, b1, W2, b2, out, E);
    return;
  }

  char* ws = (char*)d_ws;
  int2* sre  = (int2*)(ws + o_sre);
  int*  rank = (int*)(ws + o_rank);
  int*  cnt  = (int*)(ws + o_cnt);
  int*  off  = (int*)(ws + o_off);
  int*  bsum = (int*)(ws + o_bsum);
  unsigned short* Abf  = (unsigned short*)(ws + o_A);
  unsigned short* Bpbf = (unsigned short*)(ws + o_Bp);

  hipMemsetAsync(cnt, 0, (size_t)N * sizeof(int), stream);

  const int eblocks = (E + TPB - 1) / TPB;
  const int nblocks4 = (4 * N + TPB - 1) / TPB;
  const int tblocks = ((N + 15) / 16 + 3) / 4;    // 4 waves/block, 16 nodes/wave

  hist_rank<<<eblocks, TPB, 0, stream>>>(ei, cnt, rank, E);
  scan_local<<<nb, SCAN_B, 0, stream>>>(cnt, off, bsum, N);
  scan_bsum<<<1, SCAN_B, 0, stream>>>(bsum, nb);
  scatter_edges<<<eblocks, TPB, 0, stream>>>(ei, ea, off, bsum, rank, sre, E);
  precompute_mfma<<<tblocks, TPB, 0, stream>>>(x, W1, b1, Abf, Bpbf, N);
  node_accum_gemm<<<nblocks4, TPB, 0, stream>>>((const unsigned int*)Abf,
                                                (const unsigned int*)Bpbf,
                                                sre, off, bsum, cnt,
                                                W2, b2, out, N);
}

// Round 8
// 204.295 us; speedup vs baseline: 1.1048x; 1.0031x over previous
//
#include <hip/hip_runtime.h>

// ModularPathwayConv round 8:
//  R7 post-mortem: precompute_mfma fixed (off top-5). fillBufferAligned 45us is
//  the HARNESS ws-poison (uncontrollable). node_accum_gemm 45us is gather-
//  LATENCY-bound (1-deep prefetch, deg x ~400cyc serialized; VALUBusy 33%).
//  Fix: 4-deep edge chunks -> 8 independent dwordx4 loads in flight per chunk,
//  deg*lat -> lat + deg*compute. Predict 45 -> ~27us.

constexpr int TPB = 256;
constexpr int SCAN_B = 1024;

typedef __attribute__((ext_vector_type(8))) short short8;
typedef __attribute__((ext_vector_type(4))) float f32x4;

// fp32 -> bf16 round-to-nearest-even
__device__ inline unsigned short f2bf(float f) {
  unsigned u = __float_as_uint(f);
  unsigned r = u + 0x7fffu + ((u >> 16) & 1u);
  return (unsigned short)(r >> 16);
}

// ---------------- CSR build ----------------

__global__ void hist_rank(const int* __restrict__ ei, int* __restrict__ cnt,
                          int* __restrict__ rank, int E) {
  int e = blockIdx.x * blockDim.x + threadIdx.x;
  if (e < E) rank[e] = atomicAdd(&cnt[ei[E + e]], 1);
}

__global__ __launch_bounds__(SCAN_B) void scan_local(const int* __restrict__ cnt,
                                                     int* __restrict__ off,
                                                     int* __restrict__ bsum, int N) {
  __shared__ int s[SCAN_B];
  int i = blockIdx.x * SCAN_B + (int)threadIdx.x;
  int v = (i < N) ? cnt[i] : 0;
  s[threadIdx.x] = v;
  __syncthreads();
  for (int d = 1; d < SCAN_B; d <<= 1) {
    int t = (threadIdx.x >= d) ? s[threadIdx.x - d] : 0;
    __syncthreads();
    s[threadIdx.x] += t;
    __syncthreads();
  }
  if (i < N) off[i] = s[threadIdx.x] - v;
  if (threadIdx.x == SCAN_B - 1) bsum[blockIdx.x] = s[threadIdx.x];
}

__global__ __launch_bounds__(SCAN_B) void scan_bsum(int* __restrict__ bsum, int nb) {
  __shared__ int s[SCAN_B];
  int v = ((int)threadIdx.x < nb) ? bsum[threadIdx.x] : 0;
  s[threadIdx.x] = v;
  __syncthreads();
  for (int d = 1; d < SCAN_B; d <<= 1) {
    int t = (threadIdx.x >= d) ? s[threadIdx.x - d] : 0;
    __syncthreads();
    s[threadIdx.x] += t;
    __syncthreads();
  }
  if ((int)threadIdx.x < nb) bsum[threadIdx.x] = s[threadIdx.x] - v;
}

__global__ void scatter_edges(const int* __restrict__ ei, const float* __restrict__ ea,
                              const int* __restrict__ off, const int* __restrict__ bsum,
                              const int* __restrict__ rank, int2* __restrict__ sre, int E) {
  int e = blockIdx.x * blockDim.x + threadIdx.x;
  if (e >= E) return;
  int col = ei[E + e];
  int pos = off[col] + bsum[col >> 10] + rank[e];
  sre[pos] = make_int2(ei[e], __float_as_int(ea[e]));
}

// ---------------- precompute via MFMA: A = x@W1_top, Bp = x@W1_bot + b1 ----

__global__ __launch_bounds__(TPB) void precompute_mfma(
    const float* __restrict__ x, const float* __restrict__ W1,
    const float* __restrict__ b1,
    unsigned short* __restrict__ Abf, unsigned short* __restrict__ Bpbf, int N)
{
  __shared__ unsigned short sFrag[8 * 2 * 64 * 8];   // 16 KB

  for (int idx = threadIdx.x; idx < 8192; idx += TPB) {
    const int j  = idx & 7;
    const int l  = (idx >> 3) & 63;
    const int ks = (idx >> 9) & 1;
    const int ct = idx >> 10;
    const int k  = ks * 32 + ((l >> 4) << 3) + j;
    const int r  = k + 64 * (ct >> 2);
    const int c  = (ct & 3) * 16 + (l & 15);
    sFrag[idx] = f2bf(W1[r * 64 + c]);
  }
  __syncthreads();

  const int w = threadIdx.x >> 6;
  const int l = threadIdx.x & 63;
  const int q = l >> 4;
  const int m = l & 15;
  const int n0 = (blockIdx.x * 4 + w) * 16;
  if (n0 >= N) return;

  short8 bfrag[8][2];
#pragma unroll
  for (int ct = 0; ct < 8; ++ct)
#pragma unroll
    for (int ks = 0; ks < 2; ++ks)
      bfrag[ct][ks] =
          *reinterpret_cast<const short8*>(&sFrag[(ct * 2 + ks) * 512 + l * 8]);

  const int nA = (n0 + m < N) ? (n0 + m) : (N - 1);
  const float* xr = x + (size_t)nA * 64 + q * 8;
  short8 afrag[2];
#pragma unroll
  for (int ks = 0; ks < 2; ++ks) {
    float4 v0 = *reinterpret_cast<const float4*>(xr + ks * 32);
    float4 v1 = *reinterpret_cast<const float4*>(xr + ks * 32 + 4);
    short8 a;
    a[0] = (short)f2bf(v0.x); a[1] = (short)f2bf(v0.y);
    a[2] = (short)f2bf(v0.z); a[3] = (short)f2bf(v0.w);
    a[4] = (short)f2bf(v1.x); a[5] = (short)f2bf(v1.y);
    a[6] = (short)f2bf(v1.z); a[7] = (short)f2bf(v1.w);
    afrag[ks] = a;
  }

  f32x4 acc[8];
#pragma unroll
  for (int ct = 0; ct < 8; ++ct) {
    const float bv = (ct >= 4) ? b1[(ct - 4) * 16 + m] : 0.0f;
    acc[ct] = (f32x4){bv, bv, bv, bv};
  }

#pragma unroll
  for (int ct = 0; ct < 8; ++ct)
#pragma unroll
    for (int ks = 0; ks < 2; ++ks)
      acc[ct] = __builtin_amdgcn_mfma_f32_16x16x32_bf16(
          afrag[ks], bfrag[ct][ks], acc[ct], 0, 0, 0);

#pragma unroll
  for (int ct = 0; ct < 8; ++ct) {
    unsigned short* dst = (ct < 4) ? Abf : Bpbf;
    const int ch = (ct & 3) * 16 + m;
#pragma unroll
    for (int r = 0; r < 4; ++r) {
      const int node = n0 + q * 4 + r;
      if (node < N) dst[(size_t)node * 64 + ch] = f2bf(acc[ct][r]);
    }
  }
}

// ---------------- fused: H[n]=sum relu(ea*A[row]+Bp[n]); out[n]=H@W2+deg*b2 ----
// 4 lanes/node; 4-deep edge chunks for MLP (8 loads in flight); zero atomics.

__global__ __launch_bounds__(TPB) void node_accum_gemm(
    const unsigned int* __restrict__ Abf, const unsigned int* __restrict__ Bpbf,
    const int2* __restrict__ sre, const int* __restrict__ off,
    const int* __restrict__ bsum, const int* __restrict__ cnt,
    const float* __restrict__ W2, const float* __restrict__ b2,
    float* __restrict__ out, int N)
{
  __shared__ float sW2[64 * 64];    // 16 KB
  __shared__ float sB2[64];
  for (int i = threadIdx.x; i < 64 * 64 / 4; i += TPB)
    reinterpret_cast<float4*>(sW2)[i] = reinterpret_cast<const float4*>(W2)[i];
  if (threadIdx.x < 64) sB2[threadIdx.x] = b2[threadIdx.x];
  __syncthreads();

  const int g = blockIdx.x * TPB + (int)threadIdx.x;
  const int n = g >> 2;
  const int q = g & 3;
  if (n >= N) return;

  const int start = off[n] + bsum[n >> 10];
  const int deg = cnt[n];

  float bpf[16];
  {
    const uint4* brow = reinterpret_cast<const uint4*>(Bpbf) + (size_t)n * 8 + q * 2;
    uint4 b0 = brow[0], b1v = brow[1];
    const unsigned int bu[8] = {b0.x, b0.y, b0.z, b0.w, b1v.x, b1v.y, b1v.z, b1v.w};
#pragma unroll
    for (int j = 0; j < 8; ++j) {
      bpf[2 * j]     = __uint_as_float(bu[j] << 16);
      bpf[2 * j + 1] = __uint_as_float(bu[j] & 0xffff0000u);
    }
  }

  float acc[16];
#pragma unroll
  for (int j = 0; j < 16; ++j) acc[j] = 0.f;

  // 4-deep chunked edge loop: 4 sre records + 8 independent A-row dwordx4
  // loads in flight, then accumulate. deg*lat -> lat + deg*compute.
  for (int t0 = 0; t0 < deg; t0 += 4) {
    const int rem = deg - t0;
    int2 er[4];
#pragma unroll
    for (int i = 0; i < 4; ++i)
      er[i] = (i < rem) ? sre[start + t0 + i] : make_int2(0, 0);

    uint4 A0[4], A1[4];
#pragma unroll
    for (int i = 0; i < 4; ++i) {
      const uint4* ar =
          reinterpret_cast<const uint4*>(Abf) + (size_t)er[i].x * 8 + q * 2;
      A0[i] = ar[0];              // dummy lanes (i>=rem) read row 0: in-bounds,
      A1[i] = ar[1];              // never accumulated
    }

#pragma unroll
    for (int i = 0; i < 4; ++i) {
      if (i >= rem) break;
      const float eav = __int_as_float(er[i].y);
      const unsigned int au[8] = {A0[i].x, A0[i].y, A0[i].z, A0[i].w,
                                  A1[i].x, A1[i].y, A1[i].z, A1[i].w};
#pragma unroll
      for (int j = 0; j < 8; ++j) {
        float lo = __uint_as_float(au[j] << 16);
        float hi = __uint_as_float(au[j] & 0xffff0000u);
        acc[2 * j]     += fmaxf(fmaf(eav, lo, bpf[2 * j]), 0.f);
        acc[2 * j + 1] += fmaxf(fmaf(eav, hi, bpf[2 * j + 1]), 0.f);
      }
    }
  }

  // fused second GEMM: lane q owns H chunk q, produces out ch [16q,16q+16)
  float m[16];
  {
    const float degf = (float)deg;
#pragma unroll
    for (int j = 0; j < 16; j += 4) {
      float4 b = *reinterpret_cast<const float4*>(sB2 + q * 16 + j);
      m[j] = degf * b.x; m[j + 1] = degf * b.y;
      m[j + 2] = degf * b.z; m[j + 3] = degf * b.w;
    }
  }
#pragma unroll
  for (int s = 0; s < 4; ++s) {
    const int r = q ^ s;
    float hc[16];
#pragma unroll
    for (int j = 0; j < 16; ++j)
      hc[j] = (s == 0) ? acc[j] : __shfl_xor(acc[j], s);
#pragma unroll
    for (int kk = 0; kk < 16; ++kk) {
      const float hk = hc[kk];
      const float* wr = sW2 + (16 * r + kk) * 64 + q * 16;
#pragma unroll
      for (int j = 0; j < 16; j += 4) {
        float4 w = *reinterpret_cast<const float4*>(wr + j);
        m[j]     = fmaf(hk, w.x, m[j]);
        m[j + 1] = fmaf(hk, w.y, m[j + 1]);
        m[j + 2] = fmaf(hk, w.z, m[j + 2]);
        m[j + 3] = fmaf(hk, w.w, m[j + 3]);
      }
    }
  }

  float4* orow = reinterpret_cast<float4*>(out + (size_t)n * 64) + q * 4;
#pragma unroll
  for (int j = 0; j < 16; j += 4)
    orow[j / 4] = make_float4(m[j], m[j + 1], m[j + 2], m[j + 3]);
}

// ---------------- fallback (round-1 path, if ws too small) ----------------

__global__ __launch_bounds__(TPB) void edge_mlp_atomic(
    const float* __restrict__ x, const int* __restrict__ ei,
    const float* __restrict__ eattr, const float* __restrict__ W1,
    const float* __restrict__ b1, const float* __restrict__ W2,
    const float* __restrict__ b2, float* __restrict__ out, int E)
{
  __shared__ float sW1[128 * 64];
  __shared__ float sW2[64 * 64];
  __shared__ float sB1[64];
  __shared__ float sB2[64];
  for (int i = threadIdx.x; i < 128 * 64 / 4; i += TPB)
    reinterpret_cast<float4*>(sW1)[i] = reinterpret_cast<const float4*>(W1)[i];
  for (int i = threadIdx.x; i < 64 * 64 / 4; i += TPB)
    reinterpret_cast<float4*>(sW2)[i] = reinterpret_cast<const float4*>(W2)[i];
  if (threadIdx.x < 64) { sB1[threadIdx.x] = b1[threadIdx.x]; sB2[threadIdx.x] = b2[threadIdx.x]; }
  __syncthreads();
  const int e = blockIdx.x * TPB + (int)threadIdx.x;
  if (e >= E) return;
  const int row = ei[e];
  const int col = ei[E + e];
  const float scale = eattr[e];
  float h[64];
#pragma unroll
  for (int o = 0; o < 64; ++o) h[o] = sB1[o];
#pragma unroll
  for (int half = 0; half < 2; ++half) {
    const float4* src = reinterpret_cast<const float4*>(x + (size_t)(half ? col : row) * 64);
    const float sc = half ? 1.0f : scale;
    const float* wb = sW1 + half * 64 * 64;
    for (int kc = 0; kc < 16; ++kc) {
      float4 cv = src[kc];
      cv.x *= sc; cv.y *= sc; cv.z *= sc; cv.w *= sc;
      const float* wr = wb + kc * 4 * 64;
#pragma unroll
      for (int kk = 0; kk < 4; ++kk) {
        const float c = (&cv.x)[kk];
#pragma unroll
        for (int o = 0; o < 64; ++o) h[o] = fmaf(c, wr[kk * 64 + o], h[o]);
      }
    }
  }
#pragma unroll
  for (int o = 0; o < 64; ++o) h[o] = fmaxf(h[o], 0.0f);
  float* outrow = out + (size_t)col * 64;
#pragma unroll
  for (int oc = 0; oc < 4; ++oc) {
    float m[16];
#pragma unroll
    for (int j = 0; j < 16; ++j) m[j] = sB2[oc * 16 + j];
#pragma unroll
    for (int k = 0; k < 64; ++k) {
      const float hk = h[k];
      const float* wr = sW2 + k * 64 + oc * 16;
#pragma unroll
      for (int j = 0; j < 16; ++j) m[j] = fmaf(hk, wr[j], m[j]);
    }
#pragma unroll
    for (int j = 0; j < 16; ++j) atomicAdd(outrow + oc * 16 + j, m[j]);
  }
}

// ---------------- launch ----------------

extern "C" void kernel_launch(void* const* d_in, const int* in_sizes, int n_in,
                              void* d_out, int out_size, void* d_ws, size_t ws_size,
                              hipStream_t stream) {
  const float* x  = (const float*)d_in[0];
  const int*   ei = (const int*)d_in[1];   // [2,E] int32
  const float* ea = (const float*)d_in[2];
  const float* W1 = (const float*)d_in[3];
  const float* b1 = (const float*)d_in[4];
  const float* W2 = (const float*)d_in[5];
  const float* b2 = (const float*)d_in[6];
  float* out = (float*)d_out;
  const int E = in_sizes[2];
  const int N = in_sizes[0] / 64;
  const int nb = (N + SCAN_B - 1) / SCAN_B;

  // ws layout: sre[E] int2 | rank[E] | cnt[N] | off[N] | bsum[SCAN_B]
  //            | Abf[N*64 u16] | Bpbf[N*64 u16]
  auto align16 = [](size_t v) { return (v + 15) & ~(size_t)15; };
  size_t o_sre  = 0;
  size_t o_rank = align16(o_sre + (size_t)E * 8);
  size_t o_cnt  = align16(o_rank + (size_t)E * 4);
  size_t o_off  = align16(o_cnt + (size_t)N * 4);
  size_t o_bsum = align16(o_off + (size_t)N * 4);
  size_t o_A    = align16(o_bsum + (size_t)SCAN_B * 4);
  size_t o_Bp   = align16(o_A + (size_t)N * 128);
  size_t need   = o_Bp + (size_t)N * 128;

  if (ws_size < need || nb > SCAN_B) {
    hipMemsetAsync(d_out, 0, (size_t)out_size * sizeof(float), stream);
    const int blocks = (E + TPB - 1) / TPB;
    edge_mlp_atomic<<<blocks, TPB, 0, stream>>>(x, ei, ea, W1, b1, W2, b2, out, E);
    return;
  }

  char* ws = (char*)d_ws;
  int2* sre  = (int2*)(ws + o_sre);
  int*  rank = (int*)(ws + o_rank);
  int*  cnt  = (int*)(ws + o_cnt);
  int*  off  = (int*)(ws + o_off);
  int*  bsum = (int*)(ws + o_bsum);
  unsigned short* Abf  = (unsigned short*)(ws + o_A);
  unsigned short* Bpbf = (unsigned short*)(ws + o_Bp);

  hipMemsetAsync(cnt, 0, (size_t)N * sizeof(int), stream);

  const int eblocks = (E + TPB - 1) / TPB;
  const int nblocks4 = (4 * N + TPB - 1) / TPB;
  const int tblocks = ((N + 15) / 16 + 3) / 4;

  hist_rank<<<eblocks, TPB, 0, stream>>>(ei, cnt, rank, E);
  scan_local<<<nb, SCAN_B, 0, stream>>>(cnt, off, bsum, N);
  scan_bsum<<<1, SCAN_B, 0, stream>>>(bsum, nb);
  scatter_edges<<<eblocks, TPB, 0, stream>>>(ei, ea, off, bsum, rank, sre, E);
  precompute_mfma<<<tblocks, TPB, 0, stream>>>(x, W1, b1, Abf, Bpbf, N);
  node_accum_gemm<<<nblocks4, TPB, 0, stream>>>((const unsigned int*)Abf,
                                                (const unsigned int*)Bpbf,
                                                sre, off, bsum, cnt,
                                                W2, b2, out, N);
}